// Round 1
// baseline (182.756 us; speedup 1.0000x reference)
//
#include <hip/hip_runtime.h>
#include <math.h>

#define D_INNER 5120
#define DT_RANK 160
#define N_STATE 16
#define BATCH   256
#define KTOT    192               // 160 (dt_low) | 16 (B) | 16 (C)

// ---- K1 config: 256-thr blocks, 4 waves x 40-dd chunks, intra-block reduce ----
#define BGRP    8                 // batches per block
#define NBG     (BATCH / BGRP)    // 32
#define DDBLK   160               // dd per block (4 waves x 40)
#define NDDB    (D_INNER / DDBLK) // 32 -> SPLIT partials
#define SPLIT   32

// ---- K3 config: 256-thr blocks, 8 batches/block, grid (20,32)=640 blocks ----
#define K3_BT   8

// ---- workspace layout (float offsets) ----
#define OFF_T     0
#define SZ_T      (BATCH * KTOT)                  // 49,152
#define OFF_P     (OFF_T + SZ_T)
#define SZ_P      (SPLIT * BATCH * KTOT)          // 1,572,864 (6.3 MB)
#define OFF_SBC   (OFF_P + SZ_P)                  // sbc[b] = sum_n T[b][160+n]*T[b][176+n]

// ---------------------------------------------------------------------------
// K1: projection GEMM partials (unchanged, ~10 us).
// ---------------------------------------------------------------------------
__global__ __launch_bounds__(256) void k1_gemm(const float* __restrict__ x,
                                               const float* __restrict__ Wdtlow,
                                               const float* __restrict__ WB,
                                               const float* __restrict__ WC,
                                               float* __restrict__ ws) {
    __shared__ float lds[4 * BGRP * KTOT];   // 6144 floats = 24 KB
    const int tid  = threadIdx.x;
    const int lane = tid & 63;
    const int wv   = tid >> 6;               // wave 0..3
    const int b0   = blockIdx.x * BGRP;
    const int ddB  = blockIdx.y * DDBLK;

    float* xs = lds;
    for (int j = tid; j < (BGRP * DDBLK) / 4; j += 256) {   // 320 float4
        int i  = j / (DDBLK / 4);
        int c4 = j % (DDBLK / 4);
        float4 v = *(const float4*)(x + (size_t)(b0 + i) * D_INNER + ddB + c4 * 4);
        *(float4*)(xs + i * DDBLK + c4 * 4) = v;
    }
    __syncthreads();

    const int dd0 = wv * 40;
    const float* p0 = Wdtlow + (size_t)(ddB + dd0) * DT_RANK + lane;
    const float* p1 = p0 + 64;
    const float* p2;
    int st2;
    if (lane < 32)      { p2 = p0 + 128;                                          st2 = DT_RANK; }
    else if (lane < 48) { p2 = WB + (size_t)(ddB + dd0) * N_STATE + (lane - 32);  st2 = N_STATE; }
    else                { p2 = WC + (size_t)(ddB + dd0) * N_STATE + (lane - 48);  st2 = N_STATE; }

    float acc0[BGRP], acc1[BGRP], acc2[BGRP];
#pragma unroll
    for (int i = 0; i < BGRP; ++i) { acc0[i] = 0.f; acc1[i] = 0.f; acc2[i] = 0.f; }

#pragma unroll 2
    for (int g = 0; g < 10; ++g) {           // 4 dd per group
        float w0[4], w1[4], w2[4];
#pragma unroll
        for (int u = 0; u < 4; ++u) {
            int dd = g * 4 + u;
            w0[u] = p0[(size_t)dd * DT_RANK];
            w1[u] = p1[(size_t)dd * DT_RANK];
            w2[u] = p2[(size_t)dd * st2];
        }
#pragma unroll
        for (int i = 0; i < BGRP; ++i) {
            float4 xv = *(const float4*)(xs + i * DDBLK + dd0 + g * 4);
            acc0[i] += xv.x * w0[0] + xv.y * w0[1] + xv.z * w0[2] + xv.w * w0[3];
            acc1[i] += xv.x * w1[0] + xv.y * w1[1] + xv.z * w1[2] + xv.w * w1[3];
            acc2[i] += xv.x * w2[0] + xv.y * w2[1] + xv.z * w2[2] + xv.w * w2[3];
        }
    }
    __syncthreads();

#pragma unroll
    for (int i = 0; i < BGRP; ++i) {
        float* r = lds + wv * (BGRP * KTOT) + i * KTOT;
        r[lane]       = acc0[i];
        r[lane + 64]  = acc1[i];
        r[lane + 128] = acc2[i];
    }
    __syncthreads();

    float* P = ws + OFF_P + (size_t)blockIdx.y * (BATCH * KTOT) + (size_t)b0 * KTOT;
#pragma unroll
    for (int r = 0; r < 6; ++r) {
        int idx = tid + r * 256;
        P[idx] = lds[idx] + lds[idx + 1536] + lds[idx + 3072] + lds[idx + 4608];
    }
}

// ---------------------------------------------------------------------------
// K2: reduce split-K partials -> T[256][192], plus hoisted sbc[b].
// One block per batch b, 192 threads (3 waves), thread = column.
// Same fp32 accumulation order as before (s ascending, then n ascending),
// so numerics match the previous passing kernel bit-for-bit on T and sbc.
// ---------------------------------------------------------------------------
__global__ __launch_bounds__(192) void k2_reduce(float* __restrict__ ws) {
    __shared__ float ts[KTOT];
    const int b   = blockIdx.x;
    const int col = threadIdx.x;
    const float* P = ws + OFF_P + (size_t)b * KTOT + col;
    float a = 0.f;
#pragma unroll
    for (int s = 0; s < SPLIT; ++s) a += P[(size_t)s * (BATCH * KTOT)];
    ws[OFF_T + b * KTOT + col] = a;
    ts[col] = a;
    __syncthreads();
    if (col == 0) {
        float s2 = 0.f;
#pragma unroll
        for (int n = 0; n < N_STATE; ++n) s2 += ts[160 + n] * ts[176 + n];
        ws[OFF_SBC + b] = s2;
    }
}

// ---------------------------------------------------------------------------
// K3: fused delta GEMM + softplus + scan.
// Changes this round:
//  - K3_BT 4 -> 8: halves Wdt L2 re-reads (210 -> 105 MB) and T s_load traffic.
//  - sbc[b] read from K2 (1 s_load) instead of 16 FMA + 32 s_loads per (b,d).
//  - h0 batches 0,1 + all 8 x values prefetched BEFORE the GEMM (latency
//    hides under the 1280-FMA GEMM phase); 2-deep h0 pipeline in the scan.
//  - y accumulated in 4 partials: exp dependency chain 16 -> 4 serial steps.
// __launch_bounds__(256,4): VGPR cap 128 (~106 est.); grid (20,32)=640 blocks
// -> 2.5 blocks/CU = 10 waves/CU. Little's law: 10 waves x 4-8 KB h0 in
// flight >> 9.2 KB/CU needed for 6.3 TB/s, so the occupancy drop is safe.
// ---------------------------------------------------------------------------
__global__ __launch_bounds__(256, 4) void k3_fused(const float* __restrict__ Wdt,
                                                   const float* __restrict__ b_dt,
                                                   const float* __restrict__ x,
                                                   const float* __restrict__ A,
                                                   const float* __restrict__ Dv,
                                                   const float* __restrict__ h0,
                                                   const float* __restrict__ ws,
                                                   float* __restrict__ out) {
    const int tid = threadIdx.x;
    const int d   = blockIdx.x * 256 + tid;
    const int b0  = blockIdx.y * K3_BT;
    const float* T  = ws + OFF_T;
    const float* SB = ws + OFF_SBC;

    // ---- prefetch h0 batches 0,1 and all x values (overlap with GEMM) ----
    const float4* hb = (const float4*)(h0 + ((size_t)b0 * D_INNER + d) * N_STATE);
    const size_t  hstride = (size_t)D_INNER * 4;     // float4s per batch step

    float4 hc0 = hb[0], hc1 = hb[1], hc2 = hb[2], hc3 = hb[3];
    const float4* h1p = hb + hstride;
    float4 hn0 = h1p[0], hn1 = h1p[1], hn2 = h1p[2], hn3 = h1p[3];

    float xv[K3_BT];
#pragma unroll
    for (int i = 0; i < K3_BT; ++i) xv[i] = x[(size_t)(b0 + i) * D_INNER + d];

    const float bdt = b_dt[d];
    const float Dd  = Dv[d];
    const float4* a4 = (const float4*)(A + (size_t)d * N_STATE);
    float4 a0 = a4[0], a1 = a4[1], a2 = a4[2], a3 = a4[3];

    // ---- delta pre-activation GEMM: acc[i] = T[b0+i][0..159] . Wdt[:,d] ----
    // T rows are wave-uniform -> s_loads; Wdt k-major coalesced (1KB/wave/k).
    float acc[K3_BT] = {0.f, 0.f, 0.f, 0.f, 0.f, 0.f, 0.f, 0.f};
#pragma unroll 4
    for (int k = 0; k < DT_RANK; ++k) {
        float w = Wdt[(size_t)k * D_INNER + d];
#pragma unroll
        for (int i = 0; i < K3_BT; ++i)
            acc[i] += T[(size_t)(b0 + i) * KTOT + k] * w;
    }

    // ---- software-pipelined scan over 8 batches (2-deep h0 prefetch) ----
#pragma unroll
    for (int i = 0; i < K3_BT; ++i) {
        float4 p0, p1, p2, p3;
        if (i + 2 < K3_BT) {                          // prefetch batch i+2
            const float4* hp = hb + (size_t)(i + 2) * hstride;
            p0 = hp[0]; p1 = hp[1]; p2 = hp[2]; p3 = hp[3];
        }

        const int b = b0 + i;
        const float* Tb = T + (size_t)b * KTOT;       // uniform -> s_loads

        float v     = acc[i] + bdt;
        float delta = (v > 20.f) ? v : log1pf(__expf(v));
        float sbc   = SB[b];                          // hoisted to K2

        float y0, y1, y2, y3;                         // 4 partials: short chains
        y0  = __expf(delta * a0.x) * hc0.x * Tb[176 + 0];
        y0 += __expf(delta * a0.y) * hc0.y * Tb[176 + 1];
        y0 += __expf(delta * a0.z) * hc0.z * Tb[176 + 2];
        y0 += __expf(delta * a0.w) * hc0.w * Tb[176 + 3];
        y1  = __expf(delta * a1.x) * hc1.x * Tb[176 + 4];
        y1 += __expf(delta * a1.y) * hc1.y * Tb[176 + 5];
        y1 += __expf(delta * a1.z) * hc1.z * Tb[176 + 6];
        y1 += __expf(delta * a1.w) * hc1.w * Tb[176 + 7];
        y2  = __expf(delta * a2.x) * hc2.x * Tb[176 + 8];
        y2 += __expf(delta * a2.y) * hc2.y * Tb[176 + 9];
        y2 += __expf(delta * a2.z) * hc2.z * Tb[176 + 10];
        y2 += __expf(delta * a2.w) * hc2.w * Tb[176 + 11];
        y3  = __expf(delta * a3.x) * hc3.x * Tb[176 + 12];
        y3 += __expf(delta * a3.y) * hc3.y * Tb[176 + 13];
        y3 += __expf(delta * a3.z) * hc3.z * Tb[176 + 14];
        y3 += __expf(delta * a3.w) * hc3.w * Tb[176 + 15];

        out[(size_t)b * D_INNER + d] = xv[i] * (Dd + delta * sbc)
                                     + ((y0 + y1) + (y2 + y3));

        if (i < K3_BT - 1) { hc0 = hn0; hc1 = hn1; hc2 = hn2; hc3 = hn3; }
        if (i + 2 < K3_BT) { hn0 = p0;  hn1 = p1;  hn2 = p2;  hn3 = p3;  }
    }
}

// ---------------------------------------------------------------------------
extern "C" void kernel_launch(void* const* d_in, const int* in_sizes, int n_in,
                              void* d_out, int out_size, void* d_ws, size_t ws_size,
                              hipStream_t stream) {
    const float* x      = (const float*)d_in[0];
    const float* Wdtlow = (const float*)d_in[1];
    const float* Wdt    = (const float*)d_in[2];
    const float* bdt    = (const float*)d_in[3];
    const float* WB     = (const float*)d_in[4];
    const float* WC     = (const float*)d_in[5];
    const float* A      = (const float*)d_in[6];
    const float* Dv     = (const float*)d_in[7];
    const float* h0     = (const float*)d_in[8];
    float* ws  = (float*)d_ws;
    float* out = (float*)d_out;

    // K1: projection GEMM partials (1024 blocks, unchanged)
    hipLaunchKernelGGL(k1_gemm, dim3(NBG, NDDB), dim3(256), 0, stream,
                       x, Wdtlow, WB, WC, ws);
    // K2: reduce partials -> T[256][192] + sbc[256] (1 block/batch, 3 waves)
    hipLaunchKernelGGL(k2_reduce, dim3(BATCH), dim3(192), 0, stream, ws);
    // K3: fused delta GEMM + scan, 8 batches/thread, grid (20,32)
    hipLaunchKernelGGL(k3_fused, dim3(D_INNER / 256, BATCH / K3_BT), dim3(256),
                       0, stream, Wdt, bdt, x, A, Dv, h0, ws, out);
}

// Round 2
// 181.488 us; speedup vs baseline: 1.0070x; 1.0070x over previous
//
#include <hip/hip_runtime.h>
#include <math.h>

#define D_INNER 5120
#define DT_RANK 160
#define N_STATE 16
#define BATCH   256
#define KTOT    192               // 160 (dt_low) | 16 (B) | 16 (C)

// ---- K1 config: 256-thr blocks, 4 waves x 40-dd chunks, intra-block reduce ----
#define BGRP    8                 // batches per block
#define NBG     (BATCH / BGRP)    // 32
#define DDBLK   160               // dd per block (4 waves x 40)
#define NDDB    (D_INNER / DDBLK) // 32 -> SPLIT partials
#define SPLIT   32

// ---- K3a config: delta GEMM, 4 batches/block, grid (20,64)=1280 blocks ----
#define K3A_BT  4

// ---- workspace layout (float offsets) ----
#define OFF_T     0
#define SZ_T      (BATCH * KTOT)                  // 49,152
#define OFF_P     (OFF_T + SZ_T)
#define SZ_P      (SPLIT * BATCH * KTOT)          // 1,572,864 (6.3 MB)
#define OFF_SBC   (OFF_P + SZ_P)                  // sbc[b]
#define OFF_DELTA (OFF_SBC + BATCH)               // delta[B][D] (5.2 MB)

// ---------------------------------------------------------------------------
// K1: projection GEMM partials (unchanged, ~10 us).
// ---------------------------------------------------------------------------
__global__ __launch_bounds__(256) void k1_gemm(const float* __restrict__ x,
                                               const float* __restrict__ Wdtlow,
                                               const float* __restrict__ WB,
                                               const float* __restrict__ WC,
                                               float* __restrict__ ws) {
    __shared__ float lds[4 * BGRP * KTOT];   // 6144 floats = 24 KB
    const int tid  = threadIdx.x;
    const int lane = tid & 63;
    const int wv   = tid >> 6;               // wave 0..3
    const int b0   = blockIdx.x * BGRP;
    const int ddB  = blockIdx.y * DDBLK;

    float* xs = lds;
    for (int j = tid; j < (BGRP * DDBLK) / 4; j += 256) {   // 320 float4
        int i  = j / (DDBLK / 4);
        int c4 = j % (DDBLK / 4);
        float4 v = *(const float4*)(x + (size_t)(b0 + i) * D_INNER + ddB + c4 * 4);
        *(float4*)(xs + i * DDBLK + c4 * 4) = v;
    }
    __syncthreads();

    const int dd0 = wv * 40;
    const float* p0 = Wdtlow + (size_t)(ddB + dd0) * DT_RANK + lane;
    const float* p1 = p0 + 64;
    const float* p2;
    int st2;
    if (lane < 32)      { p2 = p0 + 128;                                          st2 = DT_RANK; }
    else if (lane < 48) { p2 = WB + (size_t)(ddB + dd0) * N_STATE + (lane - 32);  st2 = N_STATE; }
    else                { p2 = WC + (size_t)(ddB + dd0) * N_STATE + (lane - 48);  st2 = N_STATE; }

    float acc0[BGRP], acc1[BGRP], acc2[BGRP];
#pragma unroll
    for (int i = 0; i < BGRP; ++i) { acc0[i] = 0.f; acc1[i] = 0.f; acc2[i] = 0.f; }

#pragma unroll 2
    for (int g = 0; g < 10; ++g) {           // 4 dd per group
        float w0[4], w1[4], w2[4];
#pragma unroll
        for (int u = 0; u < 4; ++u) {
            int dd = g * 4 + u;
            w0[u] = p0[(size_t)dd * DT_RANK];
            w1[u] = p1[(size_t)dd * DT_RANK];
            w2[u] = p2[(size_t)dd * st2];
        }
#pragma unroll
        for (int i = 0; i < BGRP; ++i) {
            float4 xv = *(const float4*)(xs + i * DDBLK + dd0 + g * 4);
            acc0[i] += xv.x * w0[0] + xv.y * w0[1] + xv.z * w0[2] + xv.w * w0[3];
            acc1[i] += xv.x * w1[0] + xv.y * w1[1] + xv.z * w1[2] + xv.w * w1[3];
            acc2[i] += xv.x * w2[0] + xv.y * w2[1] + xv.z * w2[2] + xv.w * w2[3];
        }
    }
    __syncthreads();

#pragma unroll
    for (int i = 0; i < BGRP; ++i) {
        float* r = lds + wv * (BGRP * KTOT) + i * KTOT;
        r[lane]       = acc0[i];
        r[lane + 64]  = acc1[i];
        r[lane + 128] = acc2[i];
    }
    __syncthreads();

    float* P = ws + OFF_P + (size_t)blockIdx.y * (BATCH * KTOT) + (size_t)b0 * KTOT;
#pragma unroll
    for (int r = 0; r < 6; ++r) {
        int idx = tid + r * 256;
        P[idx] = lds[idx] + lds[idx + 1536] + lds[idx + 3072] + lds[idx + 4608];
    }
}

// ---------------------------------------------------------------------------
// K2: reduce split-K partials -> T[256][192], plus hoisted sbc[b].
// (unchanged from round 1)
// ---------------------------------------------------------------------------
__global__ __launch_bounds__(192) void k2_reduce(float* __restrict__ ws) {
    __shared__ float ts[KTOT];
    const int b   = blockIdx.x;
    const int col = threadIdx.x;
    const float* P = ws + OFF_P + (size_t)b * KTOT + col;
    float a = 0.f;
#pragma unroll
    for (int s = 0; s < SPLIT; ++s) a += P[(size_t)s * (BATCH * KTOT)];
    ws[OFF_T + b * KTOT + col] = a;
    ts[col] = a;
    __syncthreads();
    if (col == 0) {
        float s2 = 0.f;
#pragma unroll
        for (int n = 0; n < N_STATE; ++n) s2 += ts[160 + n] * ts[176 + n];
        ws[OFF_SBC + b] = s2;
    }
}

// ---------------------------------------------------------------------------
// K3a: delta pre-activation GEMM + softplus -> ws[OFF_DELTA].
// Round-2 split: the fused K3 was LATENCY-bound (13% HBM, 19% VALU, 21% occ,
// 640 blocks = 1.7 waves/SIMD). This kernel keeps batch-blocking for Wdt
// reuse but runs 1280 blocks (5 blocks/CU, ~20 waves/CU) with tiny VGPR.
// Work: 210M FMA (2.7us issue) + 210MB Wdt L2 traffic (~6us) -> ~7us.
// ---------------------------------------------------------------------------
__global__ __launch_bounds__(256, 8) void k3a_delta(const float* __restrict__ Wdt,
                                                    const float* __restrict__ b_dt,
                                                    float* __restrict__ ws) {
    const int tid = threadIdx.x;
    const int d   = blockIdx.x * 256 + tid;
    const int b0  = blockIdx.y * K3A_BT;
    const float* T = ws + OFF_T;

    // T rows wave-uniform -> scalar loads; Wdt k-major coalesced (1KB/wave/k).
    float acc[K3A_BT] = {0.f, 0.f, 0.f, 0.f};
#pragma unroll 8
    for (int k = 0; k < DT_RANK; ++k) {
        float w = Wdt[(size_t)k * D_INNER + d];
#pragma unroll
        for (int i = 0; i < K3A_BT; ++i)
            acc[i] += T[(size_t)(b0 + i) * KTOT + k] * w;
    }

    const float bdt = b_dt[d];
#pragma unroll
    for (int i = 0; i < K3A_BT; ++i) {
        float v     = acc[i] + bdt;
        float delta = (v > 20.f) ? v : log1pf(__expf(v));
        ws[OFF_DELTA + (size_t)(b0 + i) * D_INNER + d] = delta;   // coalesced
    }
}

// ---------------------------------------------------------------------------
// K3b: pure streaming scan. One thread per (b,d); grid (20,256) = 5120 blocks
// -> 20 blocks/CU, up to 32 waves/CU (VGPR ~48, no LDS). Reads h0 (84MB,
// 64B/lane coalesced) + delta/x (5.2MB each) + A (L2-resident) + uniform
// T/sbc s_loads; writes out (5.2MB). Pure MLP streaming -> HBM-BW-bound:
// ~100MB / 6.3TB/s ~= 16us. VALU ceiling ~72TB/s-equivalent, not a limit.
// ---------------------------------------------------------------------------
__global__ __launch_bounds__(256, 8) void k3b_scan(const float* __restrict__ x,
                                                   const float* __restrict__ A,
                                                   const float* __restrict__ Dv,
                                                   const float* __restrict__ h0,
                                                   const float* __restrict__ ws,
                                                   float* __restrict__ out) {
    const int tid = threadIdx.x;
    const int d   = blockIdx.x * 256 + tid;
    const int b   = blockIdx.y;
    const float* Tb = ws + OFF_T + (size_t)b * KTOT;   // uniform -> s_loads

    // issue longest-latency loads first (h0 from HBM)
    const float4* hp = (const float4*)(h0 + ((size_t)b * D_INNER + d) * N_STATE);
    float4 h0v = hp[0], h1v = hp[1], h2v = hp[2], h3v = hp[3];

    const float4* a4 = (const float4*)(A + (size_t)d * N_STATE);
    float4 a0 = a4[0], a1 = a4[1], a2 = a4[2], a3 = a4[3];

    const size_t bd = (size_t)b * D_INNER + d;
    float delta = ws[OFF_DELTA + bd];
    float xv    = x[bd];
    float Dd    = Dv[d];
    float sbc   = ws[OFF_SBC + b];

    float y0, y1, y2, y3;                 // 4 partials: short exp chains
    y0  = __expf(delta * a0.x) * h0v.x * Tb[176 + 0];
    y0 += __expf(delta * a0.y) * h0v.y * Tb[176 + 1];
    y0 += __expf(delta * a0.z) * h0v.z * Tb[176 + 2];
    y0 += __expf(delta * a0.w) * h0v.w * Tb[176 + 3];
    y1  = __expf(delta * a1.x) * h1v.x * Tb[176 + 4];
    y1 += __expf(delta * a1.y) * h1v.y * Tb[176 + 5];
    y1 += __expf(delta * a1.z) * h1v.z * Tb[176 + 6];
    y1 += __expf(delta * a1.w) * h1v.w * Tb[176 + 7];
    y2  = __expf(delta * a2.x) * h2v.x * Tb[176 + 8];
    y2 += __expf(delta * a2.y) * h2v.y * Tb[176 + 9];
    y2 += __expf(delta * a2.z) * h2v.z * Tb[176 + 10];
    y2 += __expf(delta * a2.w) * h2v.w * Tb[176 + 11];
    y3  = __expf(delta * a3.x) * h3v.x * Tb[176 + 12];
    y3 += __expf(delta * a3.y) * h3v.y * Tb[176 + 13];
    y3 += __expf(delta * a3.z) * h3v.z * Tb[176 + 14];
    y3 += __expf(delta * a3.w) * h3v.w * Tb[176 + 15];

    out[bd] = xv * (Dd + delta * sbc) + ((y0 + y1) + (y2 + y3));
}

// ---------------------------------------------------------------------------
extern "C" void kernel_launch(void* const* d_in, const int* in_sizes, int n_in,
                              void* d_out, int out_size, void* d_ws, size_t ws_size,
                              hipStream_t stream) {
    const float* x      = (const float*)d_in[0];
    const float* Wdtlow = (const float*)d_in[1];
    const float* Wdt    = (const float*)d_in[2];
    const float* bdt    = (const float*)d_in[3];
    const float* WB     = (const float*)d_in[4];
    const float* WC     = (const float*)d_in[5];
    const float* A      = (const float*)d_in[6];
    const float* Dv     = (const float*)d_in[7];
    const float* h0     = (const float*)d_in[8];
    float* ws  = (float*)d_ws;
    float* out = (float*)d_out;

    // K1: projection GEMM partials (1024 blocks, unchanged)
    hipLaunchKernelGGL(k1_gemm, dim3(NBG, NDDB), dim3(256), 0, stream,
                       x, Wdtlow, WB, WC, ws);
    // K2: reduce partials -> T[256][192] + sbc[256]
    hipLaunchKernelGGL(k2_reduce, dim3(BATCH), dim3(192), 0, stream, ws);
    // K3a: delta GEMM + softplus (1280 blocks, ~20 waves/CU)
    hipLaunchKernelGGL(k3a_delta, dim3(D_INNER / 256, BATCH / K3A_BT), dim3(256),
                       0, stream, Wdt, bdt, ws);
    // K3b: pure streaming scan (5120 blocks, up to 32 waves/CU)
    hipLaunchKernelGGL(k3b_scan, dim3(D_INNER / 256, BATCH), dim3(256),
                       0, stream, x, A, Dv, h0, ws, out);
}